// Round 3
// baseline (44.058 us; speedup 1.0000x reference)
//
#include <hip/hip_runtime.h>

#define BINS 10
#define TPB  256
#define NBLK 2048

// Per-thread register histograms (statically indexed -> stays in VGPRs).
// Counts as f32 are exact (<= 32 increments of <=2 per thread).

__device__ __forceinline__ void ghm_row(float p0, float p1, int t, float w0, float w1,
                                        float* __restrict__ s, float* __restrict__ c)
{
    // C=2: softmax == sigmoid and |q0-t0| == |q1-t1| == g = sigmoid(t? p0-p1 : p1-p0)
    float z = (t == 0) ? (p1 - p0) : (p0 - p1);
    float e = __expf(-z);
    float g = __fdividef(1.0f, 1.0f + e);
    int bin = min((int)(g * 10.0f), BINS - 1);

    // BCE with logits, stable form: max(p,0) - p*t + log1p(exp(-|p|))
    float l0 = __logf(1.0f + __expf(-fabsf(p0)));
    float l1 = __logf(1.0f + __expf(-fabsf(p1)));
    float bce0 = fmaxf(p0, 0.0f) - ((t == 0) ? p0 : 0.0f) + l0;
    float bce1 = fmaxf(p1, 0.0f) - ((t == 1) ? p1 : 0.0f) + l1;

    bool v0 = (w0 > 0.0f);
    bool v1 = (w1 > 0.0f);
    float wsum = (v0 ? bce0 : 0.0f) + (v1 ? bce1 : 0.0f);
    float cntf = (float)((int)v0 + (int)v1);

#pragma unroll
    for (int b = 0; b < BINS; ++b) {
        bool m = (bin == b);
        s[b] += m ? wsum : 0.0f;
        c[b] += m ? cntf : 0.0f;
    }
}

__global__ __launch_bounds__(TPB) void ghm_stage1(
    const float* __restrict__ pred, const int* __restrict__ target,
    const float* __restrict__ lw, float2* __restrict__ partial, int B)
{
    float s[BINS], c[BINS];
#pragma unroll
    for (int b = 0; b < BINS; ++b) { s[b] = 0.0f; c[b] = 0.0f; }

    const float4* p4 = (const float4*)pred;
    const float4* w4 = (const float4*)lw;
    const int2*   t2 = (const int2*)target;

    const int npairs = B >> 1;
    const int stride = gridDim.x * blockDim.x;
    for (int i = blockIdx.x * blockDim.x + threadIdx.x; i < npairs; i += stride) {
        float4 p = p4[i];
        float4 w = w4[i];
        int2   t = t2[i];
        ghm_row(p.x, p.y, t.x, w.x, w.y, s, c);
        ghm_row(p.z, p.w, t.y, w.z, w.w, s, c);
    }
    if ((B & 1) && blockIdx.x == 0 && threadIdx.x == 0) {
        int r = B - 1;
        ghm_row(pred[2 * r], pred[2 * r + 1], target[r], lw[2 * r], lw[2 * r + 1], s, c);
    }

    // wave-level reduction of the 20 register accumulators
#pragma unroll
    for (int b = 0; b < BINS; ++b) {
#pragma unroll
        for (int off = 32; off > 0; off >>= 1) {
            s[b] += __shfl_down(s[b], off);
            c[b] += __shfl_down(c[b], off);
        }
    }

    __shared__ float ss[4][BINS];
    __shared__ float sc[4][BINS];
    const int wid  = threadIdx.x >> 6;
    const int lane = threadIdx.x & 63;
    if (lane == 0) {
#pragma unroll
        for (int b = 0; b < BINS; ++b) { ss[wid][b] = s[b]; sc[wid][b] = c[b]; }
    }
    __syncthreads();

    if (threadIdx.x < BINS) {
        int b = threadIdx.x;
        float S = ss[0][b] + ss[1][b] + ss[2][b] + ss[3][b];
        float C = sc[0][b] + sc[1][b] + sc[2][b] + sc[3][b];
        partial[blockIdx.x * BINS + b] = make_float2(S, C);
    }
}

__global__ __launch_bounds__(TPB) void ghm_stage2(
    const float2* __restrict__ partial, float* __restrict__ out, int nb)
{
    double dsum[BINS];
    double dcnt[BINS];
#pragma unroll
    for (int b = 0; b < BINS; ++b) { dsum[b] = 0.0; dcnt[b] = 0.0; }

    for (int i = threadIdx.x; i < nb; i += TPB) {
#pragma unroll
        for (int b = 0; b < BINS; ++b) {
            float2 p = partial[i * BINS + b];
            dsum[b] += (double)p.x;
            dcnt[b] += (double)p.y;
        }
    }

#pragma unroll
    for (int b = 0; b < BINS; ++b) {
        for (int off = 32; off > 0; off >>= 1) {
            dsum[b] += __shfl_down(dsum[b], off);
            dcnt[b] += __shfl_down(dcnt[b], off);
        }
    }

    __shared__ double ss[4][BINS];
    __shared__ double sc[4][BINS];
    const int wid  = threadIdx.x >> 6;
    const int lane = threadIdx.x & 63;
    if (lane == 0) {
#pragma unroll
        for (int b = 0; b < BINS; ++b) { ss[wid][b] = dsum[b]; sc[wid][b] = dcnt[b]; }
    }
    __syncthreads();

    if (threadIdx.x == 0) {
        double loss = 0.0;
        int n = 0;
        for (int b = 0; b < BINS; ++b) {
            double S = ss[0][b] + ss[1][b] + ss[2][b] + ss[3][b];
            double C = sc[0][b] + sc[1][b] + sc[2][b] + sc[3][b];
            if (C > 0.0) { ++n; loss += S / C; }
        }
        if (n == 0) n = 1;
        out[0] = (float)(loss / (double)n);
    }
}

extern "C" void kernel_launch(void* const* d_in, const int* in_sizes, int n_in,
                              void* d_out, int out_size, void* d_ws, size_t ws_size,
                              hipStream_t stream)
{
    const float* pred   = (const float*)d_in[0];
    const int*   target = (const int*)d_in[1];
    const float* lw     = (const float*)d_in[2];
    const int B = in_sizes[1];

    int nb = NBLK;
    size_t need = (size_t)nb * BINS * sizeof(float2);
    if (ws_size < need) nb = (int)(ws_size / (BINS * sizeof(float2)));

    float2* partial = (float2*)d_ws;

    ghm_stage1<<<nb, TPB, 0, stream>>>(pred, target, lw, partial, B);
    ghm_stage2<<<1, TPB, 0, stream>>>(partial, (float*)d_out, nb);
}